// Round 4
// baseline (1009.828 us; speedup 1.0000x reference)
//
#include <hip/hip_runtime.h>

#define N_NODES 100000
#define N_EDGES 3200000
#define DIM 256

typedef _Float16 half_t;
typedef __attribute__((ext_vector_type(4))) _Float16 half4;
typedef __attribute__((ext_vector_type(8))) _Float16 half8;
typedef __attribute__((ext_vector_type(4))) float floatx4;

// ---------------------------------------------------------------------------
// W cast+transpose: wT[n][k] = (f16) w[k][n].
// ---------------------------------------------------------------------------
__global__ __launch_bounds__(256) void castw_kernel(const float* __restrict__ w,
                                                    half_t* __restrict__ wT) {
    __shared__ float tile[32][33];
    int bk = blockIdx.x * 32;
    int bn = blockIdx.y * 32;
    int tx = threadIdx.x & 31, ty = threadIdx.x >> 5;
#pragma unroll
    for (int i = 0; i < 4; i++)
        tile[ty + i * 8][tx] = w[(size_t)(bk + ty + i * 8) * DIM + bn + tx];
    __syncthreads();
#pragma unroll
    for (int i = 0; i < 4; i++)
        wT[(size_t)(bn + ty + i * 8) * DIM + bk + tx] = (half_t)tile[tx][ty + i * 8];
}

// ---------------------------------------------------------------------------
// MFMA GEMM: support[M,256] (f16) = x (fp32, cast in staging) @ wT^T.
// 128x128 block tile, 4 waves, BK=32, LDS rows padded to 40 f16.
// ---------------------------------------------------------------------------
#define BM 128
#define BN 128
#define BK 32
#define LDK 40

__global__ __launch_bounds__(256) void gemm_f16_kernel(const float* __restrict__ A,
                                                       const half_t* __restrict__ BT,
                                                       half_t* __restrict__ C, int M) {
    __shared__ half_t As[BM][LDK];
    __shared__ half_t Bs[BN][LDK];

    const int tid = threadIdx.x;
    const int wid = tid >> 6, lane = tid & 63;
    const int wm = wid & 1, wn = wid >> 1;
    const int row0 = blockIdx.x * BM;
    const int col0 = blockIdx.y * BN;
    const int lr = lane & 15;
    const int quad = lane >> 4;

    floatx4 acc[4][4] = {};

    const int ar = tid >> 1;
    const int ac = (tid & 1) * 16;
    const bool avalid = (row0 + ar) < M;
    const float* aptr = A + (size_t)(row0 + ar) * DIM + ac;

    for (int k0 = 0; k0 < DIM; k0 += BK) {
        {
            const float4* src = (const float4*)(aptr + k0);
            half_t* dst = &As[ar][ac];
#pragma unroll
            for (int i = 0; i < 4; i++) {
                float4 v = avalid ? src[i] : make_float4(0.f, 0.f, 0.f, 0.f);
                half4 h;
                h.x = (half_t)v.x; h.y = (half_t)v.y;
                h.z = (half_t)v.z; h.w = (half_t)v.w;
                ((half4*)dst)[i] = h;
            }
        }
        {
#pragma unroll
            for (int i = 0; i < 2; i++) {
                int ch = tid + i * 256;
                int r = ch >> 2, cb = (ch & 3) * 8;
                half8 v = *(const half8*)(BT + (size_t)(col0 + r) * DIM + k0 + cb);
                *(half8*)&Bs[r][cb] = v;
            }
        }
        __syncthreads();

        half8 a[4], b[4];
#pragma unroll
        for (int i = 0; i < 4; i++)
            a[i] = *(const half8*)&As[wm * 64 + i * 16 + lr][quad * 8];
#pragma unroll
        for (int j = 0; j < 4; j++)
            b[j] = *(const half8*)&Bs[wn * 64 + j * 16 + lr][quad * 8];
#pragma unroll
        for (int i = 0; i < 4; i++)
#pragma unroll
            for (int j = 0; j < 4; j++)
                acc[i][j] = __builtin_amdgcn_mfma_f32_16x16x32_f16(a[i], b[j], acc[i][j], 0, 0, 0);
        __syncthreads();
    }

#pragma unroll
    for (int i = 0; i < 4; i++) {
#pragma unroll
        for (int j = 0; j < 4; j++) {
            int gc = col0 + wn * 64 + j * 16 + lr;
            int grb = row0 + wm * 64 + i * 16 + quad * 4;
#pragma unroll
            for (int r = 0; r < 4; r++) {
                int gr = grb + r;
                if (gr < M) C[(size_t)gr * DIM + gc] = (half_t)acc[i][j][r];
            }
        }
    }
}

// ---------------------------------------------------------------------------
// CSR construction: histogram -> single-block scan -> permute (packed int2)
// ---------------------------------------------------------------------------
__global__ __launch_bounds__(256) void hist_kernel(const int* __restrict__ erow,
                                                   int* __restrict__ counts) {
    int i = blockIdx.x * blockDim.x + threadIdx.x;  // handles 4 edges
    if (i * 4 < N_EDGES) {
        int4 r4 = ((const int4*)erow)[i];
        atomicAdd(&counts[r4.x], 1);
        atomicAdd(&counts[r4.y], 1);
        atomicAdd(&counts[r4.z], 1);
        atomicAdd(&counts[r4.w], 1);
    }
}

__global__ __launch_bounds__(1024) void scan_kernel(int* __restrict__ counts,
                                                    int* __restrict__ offsets) {
    __shared__ int sums[1024];
    const int n = N_NODES;
    const int t = threadIdx.x;
    const int chunk = (n + 1023) / 1024;
    const int start = t * chunk;
    const int end = min(start + chunk, n);

    int local = 0;
    for (int i = start; i < end; i++) local += counts[i];
    sums[t] = local;
    __syncthreads();

    for (int off = 1; off < 1024; off <<= 1) {
        int v = (t >= off) ? sums[t - off] : 0;
        __syncthreads();
        sums[t] += v;
        __syncthreads();
    }

    int prefix = (t == 0) ? 0 : sums[t - 1];
    for (int i = start; i < end; i++) {
        int c = counts[i];
        offsets[i] = prefix;
        counts[i] = prefix;  // cursor for permute
        prefix += c;
    }
    if (t == 1023) offsets[n] = N_EDGES;
}

// epack[p] = {col, float_bits(val)} — ONE 8B scattered store per edge.
__global__ __launch_bounds__(256) void permute_kernel(const int* __restrict__ erow,
                                                      const int* __restrict__ ecol,
                                                      const float* __restrict__ eval,
                                                      int* __restrict__ cursor,
                                                      int2* __restrict__ epack) {
    int i = blockIdx.x * blockDim.x + threadIdx.x;  // handles 4 edges
    if (i * 4 >= N_EDGES) return;
    int4 r4 = ((const int4*)erow)[i];
    int4 c4 = ((const int4*)ecol)[i];
    float4 v4 = ((const float4*)eval)[i];

    int p;
    p = atomicAdd(&cursor[r4.x], 1);
    epack[p] = make_int2(c4.x, __float_as_int(v4.x));
    p = atomicAdd(&cursor[r4.y], 1);
    epack[p] = make_int2(c4.y, __float_as_int(v4.y));
    p = atomicAdd(&cursor[r4.z], 1);
    epack[p] = make_int2(c4.z, __float_as_int(v4.z));
    p = atomicAdd(&cursor[r4.w], 1);
    epack[p] = make_int2(c4.w, __float_as_int(v4.w));
}

// ---------------------------------------------------------------------------
// CSR SpMM: one wave per row; lane holds 4 dims (8 B f16); no atomics.
// ---------------------------------------------------------------------------
__global__ __launch_bounds__(256) void spmm_kernel(const half_t* __restrict__ support,
                                                   const int* __restrict__ offsets,
                                                   const int2* __restrict__ epack,
                                                   float* __restrict__ out) {
    int row = (blockIdx.x * blockDim.x + threadIdx.x) >> 6;
    int lane = threadIdx.x & 63;
    if (row >= N_NODES) return;

    int beg = offsets[row];
    int end = offsets[row + 1];

    float a0 = 0.f, a1 = 0.f, a2 = 0.f, a3 = 0.f;
    int e = beg;
    for (; e + 1 < end; e += 2) {
        int2 p0 = epack[e], p1 = epack[e + 1];
        float v0 = __int_as_float(p0.y), v1 = __int_as_float(p1.y);
        half4 s0 = ((const half4*)(support + (size_t)p0.x * DIM))[lane];
        half4 s1 = ((const half4*)(support + (size_t)p1.x * DIM))[lane];
        a0 += v0 * (float)s0.x + v1 * (float)s1.x;
        a1 += v0 * (float)s0.y + v1 * (float)s1.y;
        a2 += v0 * (float)s0.z + v1 * (float)s1.z;
        a3 += v0 * (float)s0.w + v1 * (float)s1.w;
    }
    if (e < end) {
        int2 p = epack[e];
        float v = __int_as_float(p.y);
        half4 s = ((const half4*)(support + (size_t)p.x * DIM))[lane];
        a0 += v * (float)s.x;
        a1 += v * (float)s.y;
        a2 += v * (float)s.z;
        a3 += v * (float)s.w;
    }
    ((float4*)(out + (size_t)row * DIM))[lane] = make_float4(a0, a1, a2, a3);
}

extern "C" void kernel_launch(void* const* d_in, const int* in_sizes, int n_in,
                              void* d_out, int out_size, void* d_ws, size_t ws_size,
                              hipStream_t stream) {
    const float* x    = (const float*)d_in[0];
    const float* w    = (const float*)d_in[1];
    const int*   erow = (const int*)d_in[2];
    const int*   ecol = (const int*)d_in[3];
    const float* eval = (const float*)d_in[4];
    float* out = (float*)d_out;

    // workspace layout (~77.6 MB)
    char* ws = (char*)d_ws;
    half_t* support = (half_t*)ws;                       // 51,200,000 B
    int*    counts  = (int*)(ws + 51200000);             //    400,000 B (cursor)
    int*    offsets = (int*)(ws + 51600000);             //    400,004 B
    int2*   epack   = (int2*)(ws + 52000128);            // 25,600,000 B
    half_t* wT      = (half_t*)(ws + 77600128);          //    131,072 B

    hipMemsetAsync(counts, 0, N_NODES * sizeof(int), stream);

    castw_kernel<<<dim3(8, 8), 256, 0, stream>>>(w, wT);

    dim3 ggrid((N_NODES + BM - 1) / BM, DIM / BN);
    gemm_f16_kernel<<<ggrid, 256, 0, stream>>>(x, wT, support, N_NODES);

    hist_kernel<<<(N_EDGES / 4 + 255) / 256, 256, 0, stream>>>(erow, counts);
    scan_kernel<<<1, 1024, 0, stream>>>(counts, offsets);
    permute_kernel<<<(N_EDGES / 4 + 255) / 256, 256, 0, stream>>>(erow, ecol, eval,
                                                                  counts, epack);

    spmm_kernel<<<(N_NODES * 64 + 255) / 256, 256, 0, stream>>>(support, offsets,
                                                                epack, out);
}